// Round 13
// baseline (120.791 us; speedup 1.0000x reference)
//
#include <hip/hip_runtime.h>

// Problem constants
#define B_  32
#define M_  64
#define K_  36
#define DS_ 512
#define DX_ 128
#define DQ_ 512
#define H_  256

typedef __attribute__((ext_vector_type(8))) short short8v;
typedef __attribute__((ext_vector_type(4))) float float4v;

// kernP grid layout
#define APK 256             // A-pack: (rt, K-half)
#define BPK 32              // B-pack: (mat, ks)
#define PXB 288             // px: 1152/4 rows
#define QPB 32              // qpre

// bf16 hi/lo split by truncation (identical arithmetic to round 12)
__device__ __forceinline__ void bfsplit(float a, unsigned short* h,
                                        unsigned short* s) {
    const unsigned u = __float_as_uint(a);
    const unsigned short hi = (unsigned short)(u >> 16);
    const float r = a - __uint_as_float((unsigned)hi << 16);
    *h = hi;
    *s = (unsigned short)(__float_as_uint(r) >> 16);
}

// ---------------------------------------------------------------------------
// kernP (grid 608 x 512): LDS-staged operand packing for MFMA + px + qpre.
// Output layout BYTE-IDENTICAL to round 12 (kernG is the verified consumer):
//   Apk[rt][ks][l][i]: row=l&15, k=ks*32+((l>>4)<<2)+(i&3)+((i>>2)<<4)
//   Bpk[wi][ks][l][i]: col=(wi&15)*16+(l&15), same k pattern, mat=wi>>4
//  blocks [0,256):   A-pack (rt=bid>>1, half=bid&1): stage 16x256 floats
//                    coalesced -> 2 ds_read_b128/thread -> uint4 stores.
//  blocks [256,288): B-pack (ks=bw&15, mat=bw>>4): stage 32x256 floats
//                    coalesced -> 16 scalar LDS gathers -> uint4 stores.
//  blocks [288,576): px[4 rows] = x0@w_x + score_b1   (round-11 form)
//  blocks [576,608): qpre[b]    = q[b]@w_q            (round-11 form)
// ---------------------------------------------------------------------------
__global__ __launch_bounds__(512) void kernP(
    const float* __restrict__ s2,        // (2048,512)
    const float* __restrict__ x0,        // (1152,128)
    const float* __restrict__ q,         // (32,512)
    const float* __restrict__ score_w1,  // (1152,256)
    const float* __restrict__ score_b1,  // (256)
    const float* __restrict__ h_w1,      // (512,256)
    unsigned short* __restrict__ Apk_h,  // 128*16*64*8
    unsigned short* __restrict__ Apk_l,
    unsigned short* __restrict__ Bpk_h,  // 32*16*64*8
    unsigned short* __restrict__ Bpk_l,
    float* __restrict__ px,              // (1152,256)
    float* __restrict__ qpre)            // (32,256)
{
    __shared__ float stage[8192];        // 32 KB staging
    __shared__ float comb[4 * H_];       // 4 KB split-K combine (px/qpre)
    const int t   = threadIdx.x;
    const int bid = blockIdx.x;

    if (bid < APK) {                     // ---- A-pack ----
        const int rt = bid >> 1, half = bid & 1;
        const float* src = s2 + (size_t)rt * 16 * DS_ + half * 256;

        #pragma unroll
        for (int i2 = 0; i2 < 2; ++i2) { // stage 16 rows x 256 k, coalesced
            const int f2 = t * 4 + i2 * 2048;
            *(float4*)&stage[f2] =
                *(const float4*)(src + (size_t)(f2 >> 8) * DS_ + (f2 & 255));
        }
        __syncthreads();

        // thread t -> l = t&63, ksl = t>>6; elements i=0..7
        const int base = (t & 15) * 256 + (t >> 6) * 32 + (((t >> 4) & 3) << 2);
        const float4 a0 = *(const float4*)&stage[base];        // i = 0..3
        const float4 a1 = *(const float4*)&stage[base + 16];   // i = 4..7
        const float va[8] = {a0.x, a0.y, a0.z, a0.w, a1.x, a1.y, a1.z, a1.w};

        unsigned int oh[4], ol[4];
        #pragma unroll
        for (int p = 0; p < 4; ++p) {
            unsigned short h0, s0, h1, s1;
            bfsplit(va[2 * p],     &h0, &s0);
            bfsplit(va[2 * p + 1], &h1, &s1);
            oh[p] = (unsigned)h0 | ((unsigned)h1 << 16);
            ol[p] = (unsigned)s0 | ((unsigned)s1 << 16);
        }
        const size_t dst = (size_t)rt * 4096 + half * 2048 + t * 4; // uint idx
        *(uint4*)((unsigned int*)Apk_h + dst) =
            make_uint4(oh[0], oh[1], oh[2], oh[3]);
        *(uint4*)((unsigned int*)Apk_l + dst) =
            make_uint4(ol[0], ol[1], ol[2], ol[3]);

    } else if (bid < APK + BPK) {        // ---- B-pack ----
        const int bw = bid - APK;        // 0..31
        const int ks = bw & 15, mat = bw >> 4;
        const float* Wsrc = mat ? h_w1 : score_w1;   // (512,256)

        #pragma unroll
        for (int i2 = 0; i2 < 4; ++i2) { // stage 32 k-rows x 256 cols
            const int f2 = t * 4 + i2 * 2048;
            *(float4*)&stage[f2] = *(const float4*)(
                Wsrc + (size_t)(ks * 32 + (f2 >> 8)) * H_ + (f2 & 255));
        }
        __syncthreads();

        // thread t -> nt = t>>5, l = (t*2)&63 and +1; i = 0..7 each
        const int nt = t >> 5;
        const int lA = (t * 2) & 63;
        unsigned int oh[8], ol[8];
        #pragma unroll
        for (int jl = 0; jl < 2; ++jl) {
            const int l   = lA + jl;
            const int col = nt * 16 + (l & 15);
            const int kb  = (l >> 4) << 2;
            #pragma unroll
            for (int p = 0; p < 4; ++p) {
                const int i0  = 2 * p, i1 = 2 * p + 1;
                const int kk0 = kb + (i0 & 3) + ((i0 >> 2) << 4);
                const int kk1 = kb + (i1 & 3) + ((i1 >> 2) << 4);
                unsigned short h0, s0, h1, s1;
                bfsplit(stage[kk0 * 256 + col], &h0, &s0);
                bfsplit(stage[kk1 * 256 + col], &h1, &s1);
                oh[jl * 4 + p] = (unsigned)h0 | ((unsigned)h1 << 16);
                ol[jl * 4 + p] = (unsigned)s0 | ((unsigned)s1 << 16);
            }
        }
        const size_t dst =
            (size_t)(mat * 16 + nt) * 4096 + ks * 256 + (size_t)lA * 4;
        *(uint4*)((unsigned int*)Bpk_h + dst) =
            make_uint4(oh[0], oh[1], oh[2], oh[3]);
        *(uint4*)((unsigned int*)Bpk_h + dst + 4) =
            make_uint4(oh[4], oh[5], oh[6], oh[7]);
        *(uint4*)((unsigned int*)Bpk_l + dst) =
            make_uint4(ol[0], ol[1], ol[2], ol[3]);
        *(uint4*)((unsigned int*)Bpk_l + dst + 4) =
            make_uint4(ol[4], ol[5], ol[6], ol[7]);

    } else if (bid < APK + BPK + PXB) {  // ---- px blocks (K=128) ----
        const int tile = bid - (APK + BPK);
        const int h    = t & 255;
        const int kh   = __builtin_amdgcn_readfirstlane(t >> 8);
        const float* A  = x0 + (size_t)tile * 4 * DX_ + kh * 64;   // uniform
        const float* Wp = score_w1 + (size_t)(DS_ + kh * 64) * H_ + h;

        float acc[4];
        #pragma unroll
        for (int r = 0; r < 4; ++r) acc[r] = 0.f;

        #pragma unroll 2
        for (int k = 0; k < 64; k += 4) {
            const float b0 = Wp[(size_t)(k + 0) * H_];
            const float b1 = Wp[(size_t)(k + 1) * H_];
            const float b2 = Wp[(size_t)(k + 2) * H_];
            const float b3 = Wp[(size_t)(k + 3) * H_];
            #pragma unroll
            for (int r = 0; r < 4; ++r) {
                const float4 a = *(const float4*)(A + (size_t)r * DX_ + k);
                acc[r] = fmaf(a.x, b0, acc[r]);
                acc[r] = fmaf(a.y, b1, acc[r]);
                acc[r] = fmaf(a.z, b2, acc[r]);
                acc[r] = fmaf(a.w, b3, acc[r]);
            }
        }
        if (kh) {
            #pragma unroll
            for (int r = 0; r < 4; ++r) comb[r * H_ + h] = acc[r];
        }
        __syncthreads();
        if (!kh) {
            const float b1v = score_b1[h];
            float* dst = px + (size_t)tile * 4 * H_ + h;
            #pragma unroll
            for (int r = 0; r < 4; ++r)
                dst[(size_t)r * H_] = acc[r] + comb[r * H_ + h] + b1v;
        }

    } else {                             // ---- qpre blocks ----
        const int b  = bid - (APK + BPK + PXB);
        const int h  = t & 255;
        const int kh = __builtin_amdgcn_readfirstlane(t >> 8);
        const float* qp = q + (size_t)b * DQ_ + kh * 256;          // uniform
        const float* wq = score_w1 + (size_t)(DS_ + DX_ + kh * 256) * H_ + h;
        float a0 = 0.f, a1 = 0.f, a2 = 0.f, a3 = 0.f;
        #pragma unroll 2
        for (int d = 0; d < 256; d += 4) {
            const float4 q4 = *(const float4*)(qp + d);
            a0 = fmaf(q4.x, wq[(size_t)(d + 0) * H_], a0);
            a1 = fmaf(q4.y, wq[(size_t)(d + 1) * H_], a1);
            a2 = fmaf(q4.z, wq[(size_t)(d + 2) * H_], a2);
            a3 = fmaf(q4.w, wq[(size_t)(d + 3) * H_], a3);
        }
        const float s = (a0 + a1) + (a2 + a3);
        if (kh) comb[h] = s;
        __syncthreads();
        if (!kh) qpre[(size_t)b * H_ + h] = s + comb[h];
    }
}

// ---------------------------------------------------------------------------
// kernG (grid 2048 x 64): MFMA s2-GEMMs via bf16 hi/lo split.
// (byte-identical to round 12 -- verified correct)
// ---------------------------------------------------------------------------
__global__ __launch_bounds__(64) void kernG(
    const unsigned short* __restrict__ Apk_h,
    const unsigned short* __restrict__ Apk_l,
    const unsigned short* __restrict__ Bpk_h,
    const unsigned short* __restrict__ Bpk_l,
    const float* __restrict__ h_b1,      // (256)
    float* __restrict__ pre_s,           // (2048,256)
    float* __restrict__ h1r)             // (2048,256) relu(h1+b1)
{
    const int l   = threadIdx.x;
    const int bid = blockIdx.x;
    const int ns  = bid & 7;
    const int mat = (bid >> 3) & 1;
    const int rt  = bid >> 4;

    const short8v* Ah = (const short8v*)Apk_h + (size_t)rt * 16 * 64 + l;
    const short8v* Al = (const short8v*)Apk_l + (size_t)rt * 16 * 64 + l;
    const int nt0 = mat * 16 + ns * 2;
    const short8v* B0h = (const short8v*)Bpk_h + (size_t)nt0 * 16 * 64 + l;
    const short8v* B0l = (const short8v*)Bpk_l + (size_t)nt0 * 16 * 64 + l;
    const short8v* B1h = B0h + 16 * 64;
    const short8v* B1l = B0l + 16 * 64;

    float4v aA0 = {0.f, 0.f, 0.f, 0.f}, aB0 = aA0, aC0 = aA0;
    float4v aA1 = aA0, aB1 = aA0, aC1 = aA0;

    #pragma unroll 2
    for (int ks = 0; ks < 16; ++ks) {
        const short8v ah  = Ah[(size_t)ks * 64];
        const short8v al  = Al[(size_t)ks * 64];
        const short8v b0h = B0h[(size_t)ks * 64];
        const short8v b0l = B0l[(size_t)ks * 64];
        const short8v b1h = B1h[(size_t)ks * 64];
        const short8v b1l = B1l[(size_t)ks * 64];
        aA0 = __builtin_amdgcn_mfma_f32_16x16x32_bf16(ah, b0h, aA0, 0, 0, 0);
        aB0 = __builtin_amdgcn_mfma_f32_16x16x32_bf16(ah, b0l, aB0, 0, 0, 0);
        aC0 = __builtin_amdgcn_mfma_f32_16x16x32_bf16(al, b0h, aC0, 0, 0, 0);
        aA1 = __builtin_amdgcn_mfma_f32_16x16x32_bf16(ah, b1h, aA1, 0, 0, 0);
        aB1 = __builtin_amdgcn_mfma_f32_16x16x32_bf16(ah, b1l, aB1, 0, 0, 0);
        aC1 = __builtin_amdgcn_mfma_f32_16x16x32_bf16(al, b1h, aC1, 0, 0, 0);
    }

    const float4v s0 = aA0 + aB0 + aC0;
    const float4v s1 = aA1 + aB1 + aC1;

    const int row0 = rt * 16 + ((l >> 4) << 2);
    const int c0   = ns * 32 + (l & 15);

    if (!mat) {
        #pragma unroll
        for (int r = 0; r < 4; ++r) {
            pre_s[(size_t)(row0 + r) * H_ + c0]      = s0[r];
            pre_s[(size_t)(row0 + r) * H_ + c0 + 16] = s1[r];
        }
    } else {
        const float bv0 = h_b1[c0];
        const float bv1 = h_b1[c0 + 16];
        #pragma unroll
        for (int r = 0; r < 4; ++r) {
            h1r[(size_t)(row0 + r) * H_ + c0]      = fmaxf(s0[r] + bv0, 0.f);
            h1r[(size_t)(row0 + r) * H_ + c0 + 16] = fmaxf(s1[r] + bv1, 0.f);
        }
    }
}

// ---------------------------------------------------------------------------
// kern2 (grid 512 x 256): hs = h1r @ h_w2  (round-11/12 verified form)
// ---------------------------------------------------------------------------
__global__ __launch_bounds__(256) void kern2(
    const float* __restrict__ h1r,       // (2048,256) already relu'd
    const float* __restrict__ h_w2,      // (256,128)
    float* __restrict__ hs)              // (2048,128)
{
    __shared__ float A[4 * H_];
    __shared__ float part[4][DX_];
    const int t  = threadIdx.x;
    const int r0 = blockIdx.x * 4;

    {
        const int flat = t * 4;
        *(float4*)&A[flat] = *(const float4*)(h1r + (size_t)r0 * H_ + flat);
    }
    __syncthreads();

    const int fq  = (t & 31) * 4;
    const int g   = t >> 5;
    const int row = g & 3, kh = g >> 2;
    const float* ap = &A[row * H_ + kh * 128];
    const float* wp = h_w2 + (size_t)(kh * 128) * DX_ + fq;

    float4 acc = {0.f, 0.f, 0.f, 0.f};
    #pragma unroll 4
    for (int d = 0; d < 128; d += 4) {
        const float a0 = ap[d], a1 = ap[d + 1], a2 = ap[d + 2], a3 = ap[d + 3];
        const float4 w0  = *(const float4*)(wp + (size_t)(d + 0) * DX_);
        const float4 w1  = *(const float4*)(wp + (size_t)(d + 1) * DX_);
        const float4 w2v = *(const float4*)(wp + (size_t)(d + 2) * DX_);
        const float4 w3  = *(const float4*)(wp + (size_t)(d + 3) * DX_);
        acc.x = fmaf(a0, w0.x, acc.x); acc.y = fmaf(a0, w0.y, acc.y);
        acc.z = fmaf(a0, w0.z, acc.z); acc.w = fmaf(a0, w0.w, acc.w);
        acc.x = fmaf(a1, w1.x, acc.x); acc.y = fmaf(a1, w1.y, acc.y);
        acc.z = fmaf(a1, w1.z, acc.z); acc.w = fmaf(a1, w1.w, acc.w);
        acc.x = fmaf(a2, w2v.x, acc.x); acc.y = fmaf(a2, w2v.y, acc.y);
        acc.z = fmaf(a2, w2v.z, acc.z); acc.w = fmaf(a2, w2v.w, acc.w);
        acc.x = fmaf(a3, w3.x, acc.x); acc.y = fmaf(a3, w3.y, acc.y);
        acc.z = fmaf(a3, w3.z, acc.z); acc.w = fmaf(a3, w3.w, acc.w);
    }
    if (kh) *(float4*)&part[row][fq] = acc;
    __syncthreads();
    if (!kh) {
        const float4 p = *(const float4*)&part[row][fq];
        float4 o;
        o.x = acc.x + p.x; o.y = acc.y + p.y;
        o.z = acc.z + p.z; o.w = acc.w + p.w;
        *(float4*)(hs + (size_t)(r0 + row) * DX_ + fq) = o;
    }
}

// ---------------------------------------------------------------------------
// kern3 (grid 1152, 256 threads): logits+softmax+agg. (round-11/12 verified
// form with early hs register hoist)
// ---------------------------------------------------------------------------
__global__ __launch_bounds__(256) void kern3(
    const float* __restrict__ pre_s,     // (2048,256)
    const float* __restrict__ px,        // (1152,256)
    const float* __restrict__ qpre,      // (32,256)
    const float* __restrict__ score_w2,  // (256,1)
    const float* __restrict__ hs,        // (2048,128)
    const float* __restrict__ h_b2,      // (128)
    const float* __restrict__ x0,        // (1152,128)
    float* __restrict__ out)             // (1152,256)
{
    __shared__ float logit[M_];
    __shared__ float att[M_];
    __shared__ float pr[DX_];

    const int t    = threadIdx.x;
    const int bk   = blockIdx.x;
    const int b    = bk / K_;
    const int lane = t & 63, wave = t >> 6;
    const int hq   = lane << 2;
    const int f    = t & 127, mh = t >> 7;

    float4 c4, v4;
    {
        const float4 qv = *(const float4*)(qpre + (size_t)b * H_ + hq);
        const float4 pv = *(const float4*)(px + (size_t)bk * H_ + hq);
        c4.x = qv.x + pv.x; c4.y = qv.y + pv.y;
        c4.z = qv.z + pv.z; c4.w = qv.w + pv.w;
        v4 = *(const float4*)(score_w2 + hq);
    }

    float hv[32];
    {
        const float* hsp = hs + ((size_t)b * M_ + mh * 32) * DX_ + f;
        #pragma unroll
        for (int m2 = 0; m2 < 32; ++m2)
            hv[m2] = hsp[(size_t)m2 * DX_];
    }

    const float* ps = pre_s + (size_t)b * M_ * H_;
    #pragma unroll 2
    for (int mi = 0; mi < 16; ++mi) {
        const int m = wave * 16 + mi;
        const float4 p = *(const float4*)(ps + (size_t)m * H_ + hq);
        float x = fmaxf(p.x + c4.x, 0.f) * v4.x
                + fmaxf(p.y + c4.y, 0.f) * v4.y
                + fmaxf(p.z + c4.z, 0.f) * v4.z
                + fmaxf(p.w + c4.w, 0.f) * v4.w;
        #pragma unroll
        for (int off = 32; off > 0; off >>= 1)
            x += __shfl_xor(x, off, 64);
        if (lane == 0) logit[m] = x;
    }
    __syncthreads();

    if (wave == 0) {
        const float L = logit[lane];
        float mx = L;
        #pragma unroll
        for (int off = 32; off > 0; off >>= 1)
            mx = fmaxf(mx, __shfl_xor(mx, off, 64));
        const float e = expf(L - mx);
        float sm = e;
        #pragma unroll
        for (int off = 32; off > 0; off >>= 1)
            sm += __shfl_xor(sm, off, 64);
        att[lane] = e / sm;
    }
    __syncthreads();

    {
        float r = 0.f;
        #pragma unroll
        for (int m2 = 0; m2 < 32; ++m2)
            r = fmaf(att[mh * 32 + m2], hv[m2], r);
        if (mh) pr[f] = r;
        __syncthreads();
        if (!mh)
            out[(size_t)bk * (2 * DX_) + DX_ + f] = r + pr[f] + h_b2[f];
    }
    if (t < DX_)
        out[(size_t)bk * (2 * DX_) + t] = x0[(size_t)bk * DX_ + t];
}

extern "C" void kernel_launch(void* const* d_in, const int* in_sizes, int n_in,
                              void* d_out, int out_size, void* d_ws, size_t ws_size,
                              hipStream_t stream) {
    (void)in_sizes; (void)n_in; (void)out_size; (void)ws_size;
    const float* s2       = (const float*)d_in[0];
    const float* x0       = (const float*)d_in[1];
    const float* q        = (const float*)d_in[2];
    const float* score_w1 = (const float*)d_in[3];
    const float* score_b1 = (const float*)d_in[4];
    const float* score_w2 = (const float*)d_in[5];
    // d_in[6] = score_b2 (cancels in softmax)
    const float* h_w1     = (const float*)d_in[7];
    const float* h_b1     = (const float*)d_in[8];
    const float* h_w2     = (const float*)d_in[9];
    const float* h_b2     = (const float*)d_in[10];
    float* out = (float*)d_out;

    float* ws    = (float*)d_ws;
    float* pre_s = ws;                                   // 2048*256
    float* h1r   = pre_s + (size_t)B_ * M_ * H_;         // 2048*256
    float* px    = h1r   + (size_t)B_ * M_ * H_;         // 1152*256
    float* qpre  = px    + (size_t)B_ * K_ * H_;         // 32*256
    float* hs    = qpre  + (size_t)B_ * H_;              // 2048*128

    // bf16 fragment packs at +8 MB (16B-aligned)
    unsigned short* Apk_h = (unsigned short*)(ws + 2097152);
    unsigned short* Apk_l = Apk_h + (size_t)128 * 16 * 64 * 8;
    unsigned short* Bpk_h = Apk_l + (size_t)128 * 16 * 64 * 8;
    unsigned short* Bpk_l = Bpk_h + (size_t)32 * 16 * 64 * 8;

    kernP<<<APK + BPK + PXB + QPB, 512, 0, stream>>>(
        s2, x0, q, score_w1, score_b1, h_w1,
        Apk_h, Apk_l, Bpk_h, Bpk_l, px, qpre);
    kernG<<<2048, 64, 0, stream>>>(Apk_h, Apk_l, Bpk_h, Bpk_l, h_b1,
                                   pre_s, h1r);
    kern2<<<512, 256, 0, stream>>>(h1r, h_w2, hs);
    kern3<<<B_ * K_, 256, 0, stream>>>(pre_s, px, qpre, score_w2, hs, h_b2,
                                       x0, out);
}